// Round 1
// baseline (273.746 us; speedup 1.0000x reference)
//
#include <hip/hip_runtime.h>

// SeriesDecompEMA: res = x - ma, ma = EMA(x, alpha) per (b, c) sequence over T.
// B=64, T=720, C=512, f32. Reference is mathematically ma[t] = beta*ma[t-1] + alpha*x[t],
// ma[0] = x[0], beta = 1-alpha. Chunked parallel scan: J=16 chunks of L=45.
//
// Kernel A: per-(b,j,c) thread computes chunk-local partial EMA final value s_j (seed 0).
// Kernel B: carry-in E_j = sum_{k<j} s_k * (beta^L)^(j-1-k) (Horner), re-scan chunk
//           seeded with E_j, write res and ma.

constexpr int kB = 64;
constexpr int kT = 720;
constexpr int kC = 512;
constexpr int kJ = 16;          // chunks per sequence
constexpr int kL = 45;          // chunk length; kJ*kL == kT
constexpr int kNTHREADS = kB * kJ * kC;   // 524288

__global__ __launch_bounds__(256) void ema_partials(const float* __restrict__ x,
                                                    const float* __restrict__ alphap,
                                                    float* __restrict__ s) {
    const int tid = blockIdx.x * 256 + threadIdx.x;   // = (b*kJ + j)*kC + c
    const int c   = tid & (kC - 1);
    const int bj  = tid >> 9;                         // / kC
    const int j   = bj & (kJ - 1);
    const int b   = bj >> 4;                          // / kJ
    const float alpha = alphap[0];
    const float beta  = 1.0f - alpha;

    const float* xp = x + (size_t)(b * kT + j * kL) * kC + c;

    // first element of the whole sequence has weight 1 (ma[0] = x[0]); all others alpha
    float p = ((j == 0) ? 1.0f : alpha) * xp[0];
    #pragma unroll
    for (int i = 1; i < kL; ++i)
        p = fmaf(beta, p, alpha * xp[i * kC]);

    s[tid] = p;   // layout [(b*kJ + j)*kC + c] — coalesced
}

__global__ __launch_bounds__(256) void ema_apply(const float* __restrict__ x,
                                                 const float* __restrict__ alphap,
                                                 const float* __restrict__ s,
                                                 float* __restrict__ res,
                                                 float* __restrict__ ma) {
    const int tid = blockIdx.x * 256 + threadIdx.x;
    const int c   = tid & (kC - 1);
    const int bj  = tid >> 9;
    const int j   = bj & (kJ - 1);
    const int b   = bj >> 4;
    const float alpha = alphap[0];
    const float beta  = 1.0f - alpha;
    const float betaL = powf(beta, (float)kL);   // carry decay across one chunk

    // E_j = e_{jL-1} = sum_{k<j} s_k * betaL^{j-1-k}  (Horner ascending k)
    // j is wave-uniform (wave = 64 consecutive c), so no divergence.
    const float* sp = s + (size_t)(b * kJ) * kC + c;
    float E = 0.0f;
    for (int k = 0; k < j; ++k)
        E = fmaf(E, betaL, sp[k * kC]);

    const int base = (b * kT + j * kL) * kC + c;
    const float* xp = x   + (size_t)base;
    float*       rp = res + (size_t)base;
    float*       mp = ma  + (size_t)base;

    float e = E;
    #pragma unroll
    for (int i = 0; i < kL; ++i) {
        const float xv = xp[i * kC];
        const float w  = (j == 0 && i == 0) ? 1.0f : alpha;
        e = fmaf(beta, e, w * xv);   // for j==0,i==0: e = x[0] exactly (E=0, beta*0=0)
        mp[i * kC] = e;
        rp[i * kC] = xv - e;
    }
}

extern "C" void kernel_launch(void* const* d_in, const int* in_sizes, int n_in,
                              void* d_out, int out_size, void* d_ws, size_t ws_size,
                              hipStream_t stream) {
    const float* x      = (const float*)d_in[0];
    const float* alphap = (const float*)d_in[1];
    float* res = (float*)d_out;                       // outputs concatenated: res then ma
    float* ma  = res + (size_t)kB * kT * kC;
    float* s   = (float*)d_ws;                        // kB*kJ*kC floats = 2 MB

    const int nblk = kNTHREADS / 256;                 // 2048
    ema_partials<<<nblk, 256, 0, stream>>>(x, alphap, s);
    ema_apply   <<<nblk, 256, 0, stream>>>(x, alphap, s, res, ma);
}